// Round 1
// baseline (72.140 us; speedup 1.0000x reference)
//
#include <hip/hip_runtime.h>

// Problem constants (from reference)
#define NUM_DAYS   4096
#define NUM_ATTR   512
#define MB_WIN     128
#define HID        500
#define NUM_BATCHES (NUM_DAYS - MB_WIN)        // 3968
#define NUM_Y       (NUM_BATCHES + MB_WIN - 1) // 4095 distinct day indices used
#define OUT_ELEMS   (NUM_BATCHES * MB_WIN)     // 507904

// ---------------------------------------------------------------------------
// Kernel 1: one wave per output element.
//   blocks 0..511 : v[a] = sum_h W1[a,h] * W2[h]
//   block  512    : c    = sum_h b1[h]  * W2[h] + b2
// W1 is row-major [512,500]; lane-strided reads within a row are coalesced.
// ---------------------------------------------------------------------------
__global__ __launch_bounds__(64) void k_fold_weights(
    const float* __restrict__ W1, const float* __restrict__ b1,
    const float* __restrict__ W2, const float* __restrict__ b2,
    float* __restrict__ v, float* __restrict__ c) {
    const int b    = blockIdx.x;
    const int lane = threadIdx.x;  // 0..63
    float acc = 0.f;
    if (b < NUM_ATTR) {
        const float* row = W1 + (size_t)b * HID;
        for (int h = lane; h < HID; h += 64) acc += row[h] * W2[h];
    } else {
        for (int h = lane; h < HID; h += 64) acc += b1[h] * W2[h];
    }
    #pragma unroll
    for (int off = 32; off >= 1; off >>= 1) acc += __shfl_down(acc, off, 64);
    if (lane == 0) {
        if (b < NUM_ATTR) v[b] = acc;
        else              *c   = acc + b2[0];
    }
}

// ---------------------------------------------------------------------------
// Kernel 2: one wave per day.  y[d] = x[d,:] . v + c
// 512 floats/row = 128 float4; lane l reads float4 #l and #(l+64) -> fully
// coalesced 1 KiB-per-instruction loads.
// ---------------------------------------------------------------------------
__global__ __launch_bounds__(64) void k_day_dot(
    const float* __restrict__ x, const float* __restrict__ v,
    const float* __restrict__ c, float* __restrict__ y) {
    const int d    = blockIdx.x;   // 0..NUM_Y-1
    const int lane = threadIdx.x;  // 0..63
    const float4* xr = (const float4*)(x + (size_t)d * NUM_ATTR);
    const float4* vr = (const float4*)v;
    float4 a0 = xr[lane];
    float4 a1 = xr[lane + 64];
    float4 v0 = vr[lane];
    float4 v1 = vr[lane + 64];
    float acc = a0.x * v0.x + a0.y * v0.y + a0.z * v0.z + a0.w * v0.w
              + a1.x * v1.x + a1.y * v1.y + a1.z * v1.z + a1.w * v1.w;
    #pragma unroll
    for (int off = 32; off >= 1; off >>= 1) acc += __shfl_down(acc, off, 64);
    if (lane == 0) y[d] = acc + *c;
}

// ---------------------------------------------------------------------------
// Kernel 3: scatter.  out[w*128 + m] = y[w + m].
// Each thread emits 4 consecutive outputs (same window: 128 % 4 == 0) as one
// aligned float4 store; the 4 y reads are unaligned-consecutive scalar loads
// from a 16 KiB L1/L2-resident array.
// ---------------------------------------------------------------------------
__global__ __launch_bounds__(256) void k_scatter(
    const float* __restrict__ y, float* __restrict__ out) {
    const int i    = blockIdx.x * blockDim.x + threadIdx.x; // vec4 index
    const int base = i << 2;                                // < OUT_ELEMS
    const int w    = base >> 7;
    const int m    = base & 127;
    const int d    = w + m;
    float4 r;
    r.x = y[d];
    r.y = y[d + 1];
    r.z = y[d + 2];
    r.w = y[d + 3];
    ((float4*)out)[i] = r;
}

extern "C" void kernel_launch(void* const* d_in, const int* in_sizes, int n_in,
                              void* d_out, int out_size, void* d_ws, size_t ws_size,
                              hipStream_t stream) {
    const float* x  = (const float*)d_in[0];  // [4096, 512]
    const float* W1 = (const float*)d_in[1];  // [512, 500]
    const float* b1 = (const float*)d_in[2];  // [500]
    const float* W2 = (const float*)d_in[3];  // [500, 1]
    const float* b2 = (const float*)d_in[4];  // [1]
    float* out = (float*)d_out;               // [507904]

    float* ws = (float*)d_ws;
    float* v  = ws;          // 512 floats
    float* c  = ws + 512;    // 1 float
    float* y  = ws + 1024;   // NUM_Y floats (offset keeps out-stores float4 aligned)

    k_fold_weights<<<NUM_ATTR + 1, 64, 0, stream>>>(W1, b1, W2, b2, v, c);
    k_day_dot<<<NUM_Y, 64, 0, stream>>>(x, v, c, y);
    k_scatter<<<OUT_ELEMS / 4 / 256, 256, 0, stream>>>(y, out);
}